// Round 17
// baseline (302.096 us; speedup 1.0000x reference)
//
#include <hip/hip_runtime.h>
#include <hip/hip_fp16.h>
#include <cmath>

#define NROWS  65536
#define DIM    512
#define KCODES 2048
#define NDTOT  33554432LL   // NROWS*DIM
// refine trigger: f16-product error (14*sigma = 0.0625) + key truncation (0.001)
#define MARGIN_P 0.0635f

typedef __attribute__((ext_vector_type(8))) _Float16 f16x8;  // 8 f16 = 1 MFMA operand
typedef __attribute__((ext_vector_type(4))) float f32x4;

// branchless sorted-top3 insert of packed key v (u32 min/max keep regs, no addresses)
#define KINS3(K1,K2,K3,V) do {                       \
    unsigned int _v = (V);                           \
    unsigned int _h1 = max((K1), _v); (K1) = min((K1), _v); \
    unsigned int _h2 = max((K2), _h1); (K2) = min((K2), _h1); \
    (K3) = min((K3), _h2);                           \
} while (0)

// in-place merge of two sorted triples (A <- merge(A,B)), packed-key order
#define MRG3(A1,A2,A3,B1,B2,B3) do {                               \
    unsigned int _x1 = min((A1),(B1)), _y1 = max((A1),(B1));       \
    unsigned int _x2 = min((A2),(B2)), _y2 = max((A2),(B2));       \
    unsigned int _x3 = min((A3),(B3));                             \
    (A1) = _x1; (A2) = min(_y1,_x2);                               \
    (A3) = min(max(_y1,_x2), min(_x3,_y2));                        \
} while (0)

// key pack: dist+1024 in [1024,2048) -> exponent constant -> keep mantissa[22:2]
// in key[31:11], col in key[10:0]. umin order == (dist, col) lex order.
#define FDEC(K) (__uint_as_float(0x44800000u | ((((K) >> 11) & 0x1FFFFFu) << 2)) - 1024.f)

// ---------------- kernel 1: w -> f16 B-tile order + norms ----------------
// tile (cb 4 of 512 cols, ks32 16): 32768 B = [fcol 32][lane 64][16B];
// lane = ((k%32)/8)*16 + col%16, fcol = (col%512)/16.
__global__ __launch_bounds__(256) void k_prepw(const float* __restrict__ src,
                                               char* __restrict__ dst,
                                               float* __restrict__ norms) {
    long gid = (long)blockIdx.x * 256 + threadIdx.x;
    int c  = (int)(gid >> 6);
    int k8 = (int)(gid & 63);
    const float4* s = (const float4*)(src + (size_t)c * DIM + k8 * 8);
    float4 v0 = s[0], v1 = s[1];
    float vv[8] = {v0.x, v0.y, v0.z, v0.w, v1.x, v1.y, v1.z, v1.w};
    unsigned int hw[4];
    float nrm = 0.f;
    #pragma unroll
    for (int j = 0; j < 4; ++j) {
        unsigned int h0 = __half_as_ushort(__float2half_rn(vv[2*j]));
        unsigned int h1 = __half_as_ushort(__float2half_rn(vv[2*j+1]));
        hw[j] = h0 | (h1 << 16);
        nrm = fmaf(vv[2*j], vv[2*j], nrm);
        nrm = fmaf(vv[2*j+1], vv[2*j+1], nrm);
    }
    int cb = c >> 9, fcol = (c >> 4) & 31;
    int ks32 = k8 >> 2, sub = k8 & 3;
    int l = sub * 16 + (c & 15);
    size_t off = (size_t)((cb * 16 + ks32) * 32 + fcol) * 1024 + (size_t)l * 16;
    *(uint4*)(dst + off) = make_uint4(hw[0], hw[1], hw[2], hw[3]);
    #pragma unroll
    for (int o = 32; o; o >>= 1) nrm += __shfl_xor(nrm, o, 64);
    if ((threadIdx.x & 63) == 0) norms[c] = nrm;
}

// ---------------- kernel 2: fused x-convert + f16 MFMA GEMM + packed top-3 ----------
// 512 blocks x 1024 threads (16 waves 2x8, 4 waves/SIMD), block tile 128x512,
// wave tile 64x64 (acc[4][4], 16 MFMA/step): fragment traffic 8 B/lane/MFMA
// vs r13's 12 — the invariant all prior schedules shared. A slab frag-order
// LDS (conflict-free), converted in-kernel; B 4 frags global->reg per step
// (L1-resident tile); barrier-free main loop; cb outer (4 x 512 cols).
__global__ __launch_bounds__(1024, 1) void k_gemm(const float* __restrict__ x,
                                                  const char* __restrict__ wp,
                                                  const float* __restrict__ wnorm,
                                                  float* __restrict__ xnorm,
                                                  int* __restrict__ idxo,
                                                  int* __restrict__ cand2o,
                                                  int* __restrict__ cand3o,
                                                  float* __restrict__ bestd) {
    __shared__ char smem[139776];   // A frag-order 131072 + xnorm partials 128*17*4
    const int tid = threadIdx.x;
    const int lane = tid & 63;
    const int wid = tid >> 6;                // 0..15
    const int wr = wid >> 3, wc = wid & 7;   // wave grid 2 x 8, wave tile 64x64
    const int rb = blockIdx.x;
    float* pn = (float*)(smem + 131072);     // [128][17] xnorm partials (padded)

    f32x4 acc[4][4];
    #pragma unroll
    for (int i = 0; i < 4; ++i)
        #pragma unroll
        for (int j = 0; j < 4; ++j) acc[i][j] = (f32x4){0.f, 0.f, 0.f, 0.f};

    unsigned int k1[16], k2[16], k3[16];
    #pragma unroll
    for (int s = 0; s < 16; ++s) { k1[s] = k2[s] = k3[s] = 0xFFFFFFFFu; }

    // ---- prologue: fp32 -> f16 fragment-order LDS + xnorm partials (r13) ----
    const float* xs = x + (size_t)rb * 128 * DIM;
    const unsigned chunkbase = (unsigned)((wid >> 1) * 16384 + (wid & 1) * 8192);
    #pragma unroll
    for (int frow = 0; frow < 8; ++frow) {
        int row = frow * 16 + (lane & 15);
        const float* src = xs + (size_t)row * DIM + wid * 32 + (lane >> 4) * 8;
        float4 u0 = *(const float4*)(src);
        float4 u1 = *(const float4*)(src + 4);
        unsigned int p0 = (unsigned int)__half_as_ushort(__float2half_rn(u0.x))
                        | ((unsigned int)__half_as_ushort(__float2half_rn(u0.y)) << 16);
        unsigned int p1 = (unsigned int)__half_as_ushort(__float2half_rn(u0.z))
                        | ((unsigned int)__half_as_ushort(__float2half_rn(u0.w)) << 16);
        unsigned int p2 = (unsigned int)__half_as_ushort(__float2half_rn(u1.x))
                        | ((unsigned int)__half_as_ushort(__float2half_rn(u1.y)) << 16);
        unsigned int p3 = (unsigned int)__half_as_ushort(__float2half_rn(u1.z))
                        | ((unsigned int)__half_as_ushort(__float2half_rn(u1.w)) << 16);
        *(uint4*)(smem + chunkbase + frow * 1024 + lane * 16) = make_uint4(p0, p1, p2, p3);
        float nr = u0.x * u0.x;
        nr = fmaf(u0.y, u0.y, nr); nr = fmaf(u0.z, u0.z, nr); nr = fmaf(u0.w, u0.w, nr);
        nr = fmaf(u1.x, u1.x, nr); nr = fmaf(u1.y, u1.y, nr);
        nr = fmaf(u1.z, u1.z, nr); nr = fmaf(u1.w, u1.w, nr);
        nr += __shfl_xor(nr, 16, 64);
        nr += __shfl_xor(nr, 32, 64);        // lanes 0-15: row partial over 32 dims
        if (lane < 16) pn[row * 17 + wid] = nr;
    }
    __syncthreads();                         // A slab + partials visible
    if (tid < 128) {
        float s = 0.f;
        #pragma unroll
        for (int j = 0; j < 16; ++j) s += pn[tid * 17 + j];
        xnorm[rb * 128 + tid] = s;
    }

    // ---- barrier-free main loop: cb outer (4 x 512 cols), ks inner (16 x K=32) ----
    for (int cb = 0; cb < 4; ++cb) {
        #pragma unroll 4
        for (int ks = 0; ks < 16; ++ks) {
            int t = cb * 16 + ks;
            const char* bp = wp + ((size_t)t << 15) + (size_t)(wc * 4) * 1024
                           + (size_t)lane * 16;
            f16x8 b0 = *(const f16x8*)(bp);
            f16x8 b1 = *(const f16x8*)(bp + 1024);
            f16x8 b2 = *(const f16x8*)(bp + 2048);
            f16x8 b3 = *(const f16x8*)(bp + 3072);
            const char* a = smem + (ks >> 1) * 16384 + (ks & 1) * 8192
                          + (wr * 4) * 1024 + lane * 16;
            f16x8 a0 = *(const f16x8*)(a);
            f16x8 a1 = *(const f16x8*)(a + 1024);
            f16x8 a2 = *(const f16x8*)(a + 2048);
            f16x8 a3 = *(const f16x8*)(a + 3072);
            acc[0][0] = __builtin_amdgcn_mfma_f32_16x16x32_f16(a0, b0, acc[0][0], 0, 0, 0);
            acc[1][0] = __builtin_amdgcn_mfma_f32_16x16x32_f16(a1, b0, acc[1][0], 0, 0, 0);
            acc[2][0] = __builtin_amdgcn_mfma_f32_16x16x32_f16(a2, b0, acc[2][0], 0, 0, 0);
            acc[3][0] = __builtin_amdgcn_mfma_f32_16x16x32_f16(a3, b0, acc[3][0], 0, 0, 0);
            acc[0][1] = __builtin_amdgcn_mfma_f32_16x16x32_f16(a0, b1, acc[0][1], 0, 0, 0);
            acc[1][1] = __builtin_amdgcn_mfma_f32_16x16x32_f16(a1, b1, acc[1][1], 0, 0, 0);
            acc[2][1] = __builtin_amdgcn_mfma_f32_16x16x32_f16(a2, b1, acc[2][1], 0, 0, 0);
            acc[3][1] = __builtin_amdgcn_mfma_f32_16x16x32_f16(a3, b1, acc[3][1], 0, 0, 0);
            acc[0][2] = __builtin_amdgcn_mfma_f32_16x16x32_f16(a0, b2, acc[0][2], 0, 0, 0);
            acc[1][2] = __builtin_amdgcn_mfma_f32_16x16x32_f16(a1, b2, acc[1][2], 0, 0, 0);
            acc[2][2] = __builtin_amdgcn_mfma_f32_16x16x32_f16(a2, b2, acc[2][2], 0, 0, 0);
            acc[3][2] = __builtin_amdgcn_mfma_f32_16x16x32_f16(a3, b2, acc[3][2], 0, 0, 0);
            acc[0][3] = __builtin_amdgcn_mfma_f32_16x16x32_f16(a0, b3, acc[0][3], 0, 0, 0);
            acc[1][3] = __builtin_amdgcn_mfma_f32_16x16x32_f16(a1, b3, acc[1][3], 0, 0, 0);
            acc[2][3] = __builtin_amdgcn_mfma_f32_16x16x32_f16(a2, b3, acc[2][3], 0, 0, 0);
            acc[3][3] = __builtin_amdgcn_mfma_f32_16x16x32_f16(a3, b3, acc[3][3], 0, 0, 0);
        }
        // top-3 epilogue for this 512-col block
        #pragma unroll
        for (int fc = 0; fc < 4; ++fc) {
            unsigned int col = (unsigned)(cb * 512 + wc * 64 + fc * 16 + (lane & 15));
            float wnb = wnorm[col] + 1024.f;
            #pragma unroll
            for (int fr = 0; fr < 4; ++fr) {
                #pragma unroll
                for (int reg = 0; reg < 4; ++reg) {
                    float kd = fmaf(-2.f, acc[fr][fc][reg], wnb);
                    unsigned int key = ((__float_as_uint(kd) << 9) & 0xFFFFF800u) | col;
                    int s = fr * 4 + reg;
                    KINS3(k1[s], k2[s], k3[s], key);
                }
                acc[fr][fc] = (f32x4){0.f, 0.f, 0.f, 0.f};
            }
        }
    }

    // butterfly top-3 merge across the 16 column-lanes of each slot
    #pragma unroll
    for (int s = 0; s < 16; ++s) {
        #pragma unroll
        for (int off = 1; off < 16; off <<= 1) {
            unsigned int b1 = (unsigned)__shfl_xor((int)k1[s], off, 16);
            unsigned int b2 = (unsigned)__shfl_xor((int)k2[s], off, 16);
            unsigned int b3 = (unsigned)__shfl_xor((int)k3[s], off, 16);
            MRG3(k1[s], k2[s], k3[s], b1, b2, b3);
        }
    }
    // lane (lane&15)==s owns slot s; static-unrolled select (rule #20)
    unsigned int m1 = 0, m2 = 0, m3 = 0;
    #pragma unroll
    for (int s = 0; s < 16; ++s) {
        bool mine = (lane & 15) == s;
        m1 = mine ? k1[s] : m1;
        m2 = mine ? k2[s] : m2;
        m3 = mine ? k3[s] : m3;
    }
    int sl = lane & 15;
    int rowl = wr * 64 + (sl >> 2) * 16 + (lane >> 4) * 4 + (sl & 3);
    __syncthreads();                         // MFMA loop fully done; reuse A region
    ((uint4*)smem)[rowl * 8 + wc] = make_uint4(m1, m2, m3, 0u);
    __syncthreads();
    if (tid < 128) {
        const uint4* e = (const uint4*)smem + tid * 8;
        uint4 e0 = e[0];
        unsigned int K1 = e0.x, K2 = e0.y, K3 = e0.z;
        #pragma unroll
        for (int j = 1; j < 8; ++j) {
            uint4 ej = e[j];
            MRG3(K1, K2, K3, ej.x, ej.y, ej.z);
        }
        float f1 = FDEC(K1);
        float f2 = FDEC(K2);
        float f3 = FDEC(K3);
        int row = rb * 128 + tid;
        idxo[row]   = (int)(K1 & 0x7FFu);
        bestd[row]  = f1;
        cand2o[row] = (f2 - f1 < MARGIN_P) ? (int)(K2 & 0x7FFu) : -1;
        cand3o[row] = (f3 - f1 < MARGIN_P) ? (int)(K3 & 0x7FFu) : -1;
    }
}

// ---------------- kernel 3: fused fp64 refine + gather + loss partial + histogram ----
__global__ __launch_bounds__(256) void k_gather2(const float* __restrict__ x,
                                                 const float* __restrict__ w,
                                                 const int* __restrict__ idxo,
                                                 const int* __restrict__ cand2o,
                                                 const int* __restrict__ cand3o,
                                                 const float* __restrict__ bestd,
                                                 const float* __restrict__ xnorm,
                                                 float* __restrict__ out,
                                                 int* __restrict__ hist,
                                                 double* __restrict__ part) {
    __shared__ double red[4];
    int wid = threadIdx.x >> 6, lane = threadIdx.x & 63;
    int n = blockIdx.x * 4 + wid;
    int c1 = idxo[n];
    int c2 = cand2o[n];
    int cfin = c1;
    double dist = (double)bestd[n];
    if (c2 >= 0) {
        int c3 = cand3o[n];
        int c3e = (c3 < 0) ? c1 : c3;
        const float* xr = x + (size_t)n * DIM;
        const float* w1 = w + (size_t)c1 * DIM;
        const float* w2 = w + (size_t)c2 * DIM;
        const float* w3 = w + (size_t)c3e * DIM;
        double s1 = 0.0, s2 = 0.0, s3 = 0.0;
        #pragma unroll
        for (int j = 0; j < DIM / 64; ++j) {
            int d = lane + 64 * j;
            double xv = (double)xr[d];
            double a = (double)w1[d], b = (double)w2[d], c = (double)w3[d];
            s1 += a * a - 2.0 * xv * a;
            s2 += b * b - 2.0 * xv * b;
            s3 += c * c - 2.0 * xv * c;
        }
        #pragma unroll
        for (int off = 32; off; off >>= 1) {
            s1 += __shfl_xor(s1, off, 64);
            s2 += __shfl_xor(s2, off, 64);
            s3 += __shfl_xor(s3, off, 64);
        }
        double bs = s1; int bi = c1;
        if (s2 < bs || (s2 == bs && c2 < bi)) { bs = s2; bi = c2; }
        if (c3 >= 0 && (s3 < bs || (s3 == bs && c3 < bi))) { bs = s3; bi = c3; }
        cfin = bi;
        dist = bs;
    }
    const float* wq = w + (size_t)cfin * DIM;
    float* oq = out + 1 + (size_t)n * DIM;   // quantized_st == quantized numerically
    #pragma unroll
    for (int j = 0; j < DIM / 64; ++j) {
        int d = j * 64 + lane;
        oq[d] = wq[d];
    }
    if (lane == 0) {
        red[wid] = dist + (double)xnorm[n];  // ||x-w||^2 = (||w||^2-2xw) + ||x||^2
        atomicAdd(&hist[cfin], 1);
        out[2 + NDTOT + n] = (float)cfin;
    }
    __syncthreads();
    if (threadIdx.x == 0)
        part[blockIdx.x] = red[0] + red[1] + red[2] + red[3];
}

// ---------------- kernel 4: deterministic finalize (loss + perplexity) ----------------
__global__ __launch_bounds__(256) void k_final2(const double* __restrict__ part,
                                                const int* __restrict__ hist,
                                                float* __restrict__ out) {
    __shared__ double sm[256];
    int t = threadIdx.x;
    double s = 0.0;
    for (int i = t; i < NROWS / 4; i += 256) s += part[i];
    sm[t] = s; __syncthreads();
    for (int off = 128; off; off >>= 1) { if (t < off) sm[t] += sm[t + off]; __syncthreads(); }
    if (t == 0) out[0] = (float)(sm[0] * 0.25 / (double)NDTOT);
    __syncthreads();
    double e = 0.0;
    for (int k = t; k < KCODES; k += 256) {
        double p = (double)hist[k] / (double)NROWS;
        e -= p * log(p + 1e-10);
    }
    sm[t] = e; __syncthreads();
    for (int off = 128; off; off >>= 1) { if (t < off) sm[t] += sm[t + off]; __syncthreads(); }
    if (t == 0) out[1 + NDTOT] = (float)exp(sm[0]);
}

extern "C" void kernel_launch(void* const* d_in, const int* in_sizes, int n_in,
                              void* d_out, int out_size, void* d_ws, size_t ws_size,
                              hipStream_t stream) {
    const float* x = (const float*)d_in[0];   // [64,1024,512] fp32
    const float* w = (const float*)d_in[1];   // [2048,512] fp32
    float* out = (float*)d_out;
    char* ws = (char*)d_ws;

    char*   wp    = ws;                            // 2 MB (+32KB pad)
    float*  wnorm = (float*)(ws + 2129920);        // 8 KB  (2MB + 32KB pad)
    int*    idxo  = (int*)(ws + 2138112);          // 256 KB
    int*    cand2 = (int*)(ws + 2400256);          // 256 KB
    int*    cand3 = (int*)(ws + 2662400);          // 256 KB
    int*    hist  = (int*)(ws + 2924544);          // 8 KB
    float*  xnorm = (float*)(ws + 2932736);        // 256 KB
    float*  bestd = (float*)(ws + 3194880);        // 256 KB
    double* part  = (double*)(ws + 3457024);       // 128 KB

    hipMemsetAsync(hist, 0, KCODES * sizeof(int), stream);
    k_prepw  <<<(KCODES * 64) / 256, 256, 0, stream>>>(w, wp, wnorm);
    k_gemm   <<<NROWS / 128, 1024, 0, stream>>>(x, wp, wnorm, xnorm, idxo, cand2, cand3, bestd);
    k_gather2<<<NROWS / 4, 256, 0, stream>>>(x, w, idxo, cand2, cand3, bestd, xnorm, out, hist, part);
    k_final2 <<<1, 256, 0, stream>>>(part, hist, out);
}

// Round 18
// 223.398 us; speedup vs baseline: 1.3523x; 1.3523x over previous
//
#include <hip/hip_runtime.h>
#include <hip/hip_fp16.h>
#include <cmath>

#define NROWS  65536
#define DIM    512
#define KCODES 2048
#define NDTOT  33554432LL   // NROWS*DIM
// refine trigger: f16-product error (14*sigma = 0.0625) + key truncation (0.001)
#define MARGIN_P 0.0635f

typedef __attribute__((ext_vector_type(8))) _Float16 f16x8;  // 8 f16 = 1 MFMA operand
typedef __attribute__((ext_vector_type(4))) float f32x4;

// branchless sorted-top3 insert of packed key v (u32 min/max keep regs, no addresses)
#define KINS3(K1,K2,K3,V) do {                       \
    unsigned int _v = (V);                           \
    unsigned int _h1 = max((K1), _v); (K1) = min((K1), _v); \
    unsigned int _h2 = max((K2), _h1); (K2) = min((K2), _h1); \
    (K3) = min((K3), _h2);                           \
} while (0)

// in-place merge of two sorted triples (A <- merge(A,B)), packed-key order
#define MRG3(A1,A2,A3,B1,B2,B3) do {                               \
    unsigned int _x1 = min((A1),(B1)), _y1 = max((A1),(B1));       \
    unsigned int _x2 = min((A2),(B2)), _y2 = max((A2),(B2));       \
    unsigned int _x3 = min((A3),(B3));                             \
    (A1) = _x1; (A2) = min(_y1,_x2);                               \
    (A3) = min(max(_y1,_x2), min(_x3,_y2));                        \
} while (0)

// key pack: dist+1024 in [1024,2048) -> exponent constant -> keep mantissa[22:2]
// in key[31:11], col in key[10:0]. umin order == (dist, col) lex order.
#define FDEC(K) (__uint_as_float(0x44800000u | ((((K) >> 11) & 0x1FFFFFu) << 2)) - 1024.f)

// ---------------- kernel 1: w -> f16 B-tile order + norms ----------------
// tile (cb 8 of 256 cols, ks32 16): 16384 B = [fcol 16][lane 64][16B];
// lane = ((k%32)/8)*16 + col%16, fcol = (col%256)/16.
__global__ __launch_bounds__(256) void k_prepw(const float* __restrict__ src,
                                               char* __restrict__ dst,
                                               float* __restrict__ norms) {
    long gid = (long)blockIdx.x * 256 + threadIdx.x;
    int c  = (int)(gid >> 6);
    int k8 = (int)(gid & 63);
    const float4* s = (const float4*)(src + (size_t)c * DIM + k8 * 8);
    float4 v0 = s[0], v1 = s[1];
    float vv[8] = {v0.x, v0.y, v0.z, v0.w, v1.x, v1.y, v1.z, v1.w};
    unsigned int hw[4];
    float nrm = 0.f;
    #pragma unroll
    for (int j = 0; j < 4; ++j) {
        unsigned int h0 = __half_as_ushort(__float2half_rn(vv[2*j]));
        unsigned int h1 = __half_as_ushort(__float2half_rn(vv[2*j+1]));
        hw[j] = h0 | (h1 << 16);
        nrm = fmaf(vv[2*j], vv[2*j], nrm);
        nrm = fmaf(vv[2*j+1], vv[2*j+1], nrm);
    }
    int cb = c >> 8, fcol = (c >> 4) & 15;
    int ks32 = k8 >> 2, sub = k8 & 3;
    int l = sub * 16 + (c & 15);
    size_t off = (size_t)((cb * 16 + ks32) * 16 + fcol) * 1024 + (size_t)l * 16;
    *(uint4*)(dst + off) = make_uint4(hw[0], hw[1], hw[2], hw[3]);
    #pragma unroll
    for (int o = 32; o; o >>= 1) nrm += __shfl_xor(nrm, o, 64);
    if ((threadIdx.x & 63) == 0) norms[c] = nrm;
}

// ---------------- kernel 2: fused x-convert + f16 MFMA GEMM + packed top-3 ----------
// 512 blocks x 1024 threads (16 waves, grid 2x8, wave tile 64x32, 4 waves/SIMD).
// A slab in FRAGMENT order (conflict-free: lane*16 contiguous), converted
// in-kernel; main loop barrier-free: A read-only in LDS; B fragments
// global->reg (L1-hit, tile shared by all 16 waves); 8 MFMA/step/wave;
// TLP (4 waves/SIMD) hides latency. Best measured config (223.1/224.4us).
__global__ __launch_bounds__(1024, 1) void k_gemm(const float* __restrict__ x,
                                                  const char* __restrict__ wp,
                                                  const float* __restrict__ wnorm,
                                                  float* __restrict__ xnorm,
                                                  int* __restrict__ idxo,
                                                  int* __restrict__ cand2o,
                                                  int* __restrict__ cand3o,
                                                  float* __restrict__ bestd) {
    __shared__ char smem[139776];   // A frag-order 131072 + xnorm partials 128*17*4
    const int tid = threadIdx.x;
    const int lane = tid & 63;
    const int wid = tid >> 6;                // 0..15
    const int wr = wid >> 3, wc = wid & 7;   // wave grid 2 x 8, wave tile 64x32
    const int rb = blockIdx.x;
    float* pn = (float*)(smem + 131072);     // [128][17] xnorm partials (padded)

    f32x4 acc[4][2];
    #pragma unroll
    for (int i = 0; i < 4; ++i)
        #pragma unroll
        for (int j = 0; j < 2; ++j) acc[i][j] = (f32x4){0.f, 0.f, 0.f, 0.f};

    unsigned int k1[16], k2[16], k3[16];
    #pragma unroll
    for (int s = 0; s < 16; ++s) { k1[s] = k2[s] = k3[s] = 0xFFFFFFFFu; }

    // ---- prologue: fp32 -> f16 fragment-order LDS + xnorm partials ----
    const float* xs = x + (size_t)rb * 128 * DIM;
    const unsigned chunkbase = (unsigned)((wid >> 1) * 16384 + (wid & 1) * 8192);
    #pragma unroll
    for (int frow = 0; frow < 8; ++frow) {
        int row = frow * 16 + (lane & 15);
        const float* src = xs + (size_t)row * DIM + wid * 32 + (lane >> 4) * 8;
        float4 u0 = *(const float4*)(src);
        float4 u1 = *(const float4*)(src + 4);
        unsigned int p0 = (unsigned int)__half_as_ushort(__float2half_rn(u0.x))
                        | ((unsigned int)__half_as_ushort(__float2half_rn(u0.y)) << 16);
        unsigned int p1 = (unsigned int)__half_as_ushort(__float2half_rn(u0.z))
                        | ((unsigned int)__half_as_ushort(__float2half_rn(u0.w)) << 16);
        unsigned int p2 = (unsigned int)__half_as_ushort(__float2half_rn(u1.x))
                        | ((unsigned int)__half_as_ushort(__float2half_rn(u1.y)) << 16);
        unsigned int p3 = (unsigned int)__half_as_ushort(__float2half_rn(u1.z))
                        | ((unsigned int)__half_as_ushort(__float2half_rn(u1.w)) << 16);
        *(uint4*)(smem + chunkbase + frow * 1024 + lane * 16) = make_uint4(p0, p1, p2, p3);
        float nr = u0.x * u0.x;
        nr = fmaf(u0.y, u0.y, nr); nr = fmaf(u0.z, u0.z, nr); nr = fmaf(u0.w, u0.w, nr);
        nr = fmaf(u1.x, u1.x, nr); nr = fmaf(u1.y, u1.y, nr);
        nr = fmaf(u1.z, u1.z, nr); nr = fmaf(u1.w, u1.w, nr);
        nr += __shfl_xor(nr, 16, 64);
        nr += __shfl_xor(nr, 32, 64);        // lanes 0-15: row partial over 32 dims
        if (lane < 16) pn[row * 17 + wid] = nr;
    }
    __syncthreads();                         // A slab + partials visible
    if (tid < 128) {
        float s = 0.f;
        #pragma unroll
        for (int j = 0; j < 16; ++j) s += pn[tid * 17 + j];
        xnorm[rb * 128 + tid] = s;
    }

    // ---- barrier-free main loop: cb outer (8 x 256 cols), ks inner (16 x K=32) ----
    for (int cb = 0; cb < 8; ++cb) {
        #pragma unroll 4
        for (int ks = 0; ks < 16; ++ks) {
            int t = cb * 16 + ks;
            const char* bp = wp + ((size_t)t << 14) + (size_t)(wc * 2) * 1024
                           + (size_t)lane * 16;
            f16x8 b0 = *(const f16x8*)(bp);
            f16x8 b1 = *(const f16x8*)(bp + 1024);
            const char* a = smem + (ks >> 1) * 16384 + (ks & 1) * 8192
                          + (wr * 4) * 1024 + lane * 16;
            f16x8 a0 = *(const f16x8*)(a);
            f16x8 a1 = *(const f16x8*)(a + 1024);
            f16x8 a2 = *(const f16x8*)(a + 2048);
            f16x8 a3 = *(const f16x8*)(a + 3072);
            acc[0][0] = __builtin_amdgcn_mfma_f32_16x16x32_f16(a0, b0, acc[0][0], 0, 0, 0);
            acc[1][0] = __builtin_amdgcn_mfma_f32_16x16x32_f16(a1, b0, acc[1][0], 0, 0, 0);
            acc[2][0] = __builtin_amdgcn_mfma_f32_16x16x32_f16(a2, b0, acc[2][0], 0, 0, 0);
            acc[3][0] = __builtin_amdgcn_mfma_f32_16x16x32_f16(a3, b0, acc[3][0], 0, 0, 0);
            acc[0][1] = __builtin_amdgcn_mfma_f32_16x16x32_f16(a0, b1, acc[0][1], 0, 0, 0);
            acc[1][1] = __builtin_amdgcn_mfma_f32_16x16x32_f16(a1, b1, acc[1][1], 0, 0, 0);
            acc[2][1] = __builtin_amdgcn_mfma_f32_16x16x32_f16(a2, b1, acc[2][1], 0, 0, 0);
            acc[3][1] = __builtin_amdgcn_mfma_f32_16x16x32_f16(a3, b1, acc[3][1], 0, 0, 0);
        }
        // top-3 epilogue for this 256-col block
        #pragma unroll
        for (int fc = 0; fc < 2; ++fc) {
            unsigned int col = (unsigned)(cb * 256 + wc * 32 + fc * 16 + (lane & 15));
            float wnb = wnorm[col] + 1024.f;
            #pragma unroll
            for (int fr = 0; fr < 4; ++fr) {
                #pragma unroll
                for (int reg = 0; reg < 4; ++reg) {
                    float kd = fmaf(-2.f, acc[fr][fc][reg], wnb);
                    unsigned int key = ((__float_as_uint(kd) << 9) & 0xFFFFF800u) | col;
                    int s = fr * 4 + reg;
                    KINS3(k1[s], k2[s], k3[s], key);
                }
                acc[fr][fc] = (f32x4){0.f, 0.f, 0.f, 0.f};
            }
        }
    }

    // butterfly top-3 merge across the 16 column-lanes of each slot
    #pragma unroll
    for (int s = 0; s < 16; ++s) {
        #pragma unroll
        for (int off = 1; off < 16; off <<= 1) {
            unsigned int b1 = (unsigned)__shfl_xor((int)k1[s], off, 16);
            unsigned int b2 = (unsigned)__shfl_xor((int)k2[s], off, 16);
            unsigned int b3 = (unsigned)__shfl_xor((int)k3[s], off, 16);
            MRG3(k1[s], k2[s], k3[s], b1, b2, b3);
        }
    }
    // lane (lane&15)==s owns slot s; static-unrolled select (rule #20)
    unsigned int m1 = 0, m2 = 0, m3 = 0;
    #pragma unroll
    for (int s = 0; s < 16; ++s) {
        bool mine = (lane & 15) == s;
        m1 = mine ? k1[s] : m1;
        m2 = mine ? k2[s] : m2;
        m3 = mine ? k3[s] : m3;
    }
    int sl = lane & 15;
    int rowl = wr * 64 + (sl >> 2) * 16 + (lane >> 4) * 4 + (sl & 3);
    __syncthreads();                         // MFMA loop fully done; reuse A region
    ((uint4*)smem)[rowl * 8 + wc] = make_uint4(m1, m2, m3, 0u);
    __syncthreads();
    if (tid < 128) {
        const uint4* e = (const uint4*)smem + tid * 8;
        uint4 e0 = e[0];
        unsigned int K1 = e0.x, K2 = e0.y, K3 = e0.z;
        #pragma unroll
        for (int j = 1; j < 8; ++j) {
            uint4 ej = e[j];
            MRG3(K1, K2, K3, ej.x, ej.y, ej.z);
        }
        float f1 = FDEC(K1);
        float f2 = FDEC(K2);
        float f3 = FDEC(K3);
        int row = rb * 128 + tid;
        idxo[row]   = (int)(K1 & 0x7FFu);
        bestd[row]  = f1;
        cand2o[row] = (f2 - f1 < MARGIN_P) ? (int)(K2 & 0x7FFu) : -1;
        cand3o[row] = (f3 - f1 < MARGIN_P) ? (int)(K3 & 0x7FFu) : -1;
    }
}

// ---------------- kernel 3: fused fp64 refine + gather + loss partial + histogram ----
__global__ __launch_bounds__(256) void k_gather2(const float* __restrict__ x,
                                                 const float* __restrict__ w,
                                                 const int* __restrict__ idxo,
                                                 const int* __restrict__ cand2o,
                                                 const int* __restrict__ cand3o,
                                                 const float* __restrict__ bestd,
                                                 const float* __restrict__ xnorm,
                                                 float* __restrict__ out,
                                                 int* __restrict__ hist,
                                                 double* __restrict__ part) {
    __shared__ double red[4];
    int wid = threadIdx.x >> 6, lane = threadIdx.x & 63;
    int n = blockIdx.x * 4 + wid;
    int c1 = idxo[n];
    int c2 = cand2o[n];
    int cfin = c1;
    double dist = (double)bestd[n];
    if (c2 >= 0) {
        int c3 = cand3o[n];
        int c3e = (c3 < 0) ? c1 : c3;
        const float* xr = x + (size_t)n * DIM;
        const float* w1 = w + (size_t)c1 * DIM;
        const float* w2 = w + (size_t)c2 * DIM;
        const float* w3 = w + (size_t)c3e * DIM;
        double s1 = 0.0, s2 = 0.0, s3 = 0.0;
        #pragma unroll
        for (int j = 0; j < DIM / 64; ++j) {
            int d = lane + 64 * j;
            double xv = (double)xr[d];
            double a = (double)w1[d], b = (double)w2[d], c = (double)w3[d];
            s1 += a * a - 2.0 * xv * a;
            s2 += b * b - 2.0 * xv * b;
            s3 += c * c - 2.0 * xv * c;
        }
        #pragma unroll
        for (int off = 32; off; off >>= 1) {
            s1 += __shfl_xor(s1, off, 64);
            s2 += __shfl_xor(s2, off, 64);
            s3 += __shfl_xor(s3, off, 64);
        }
        double bs = s1; int bi = c1;
        if (s2 < bs || (s2 == bs && c2 < bi)) { bs = s2; bi = c2; }
        if (c3 >= 0 && (s3 < bs || (s3 == bs && c3 < bi))) { bs = s3; bi = c3; }
        cfin = bi;
        dist = bs;
    }
    const float* wq = w + (size_t)cfin * DIM;
    float* oq = out + 1 + (size_t)n * DIM;   // quantized_st == quantized numerically
    #pragma unroll
    for (int j = 0; j < DIM / 64; ++j) {
        int d = j * 64 + lane;
        oq[d] = wq[d];
    }
    if (lane == 0) {
        red[wid] = dist + (double)xnorm[n];  // ||x-w||^2 = (||w||^2-2xw) + ||x||^2
        atomicAdd(&hist[cfin], 1);
        out[2 + NDTOT + n] = (float)cfin;
    }
    __syncthreads();
    if (threadIdx.x == 0)
        part[blockIdx.x] = red[0] + red[1] + red[2] + red[3];
}

// ---------------- kernel 4: deterministic finalize (loss + perplexity) ----------------
__global__ __launch_bounds__(256) void k_final2(const double* __restrict__ part,
                                                const int* __restrict__ hist,
                                                float* __restrict__ out) {
    __shared__ double sm[256];
    int t = threadIdx.x;
    double s = 0.0;
    for (int i = t; i < NROWS / 4; i += 256) s += part[i];
    sm[t] = s; __syncthreads();
    for (int off = 128; off; off >>= 1) { if (t < off) sm[t] += sm[t + off]; __syncthreads(); }
    if (t == 0) out[0] = (float)(sm[0] * 0.25 / (double)NDTOT);
    __syncthreads();
    double e = 0.0;
    for (int k = t; k < KCODES; k += 256) {
        double p = (double)hist[k] / (double)NROWS;
        e -= p * log(p + 1e-10);
    }
    sm[t] = e; __syncthreads();
    for (int off = 128; off; off >>= 1) { if (t < off) sm[t] += sm[t + off]; __syncthreads(); }
    if (t == 0) out[1 + NDTOT] = (float)exp(sm[0]);
}

extern "C" void kernel_launch(void* const* d_in, const int* in_sizes, int n_in,
                              void* d_out, int out_size, void* d_ws, size_t ws_size,
                              hipStream_t stream) {
    const float* x = (const float*)d_in[0];   // [64,1024,512] fp32
    const float* w = (const float*)d_in[1];   // [2048,512] fp32
    float* out = (float*)d_out;
    char* ws = (char*)d_ws;

    char*   wp    = ws;                            // 2 MB (+16KB pad)
    float*  wnorm = (float*)(ws + 2113536);        // 8 KB
    int*    idxo  = (int*)(ws + 2121728);          // 256 KB
    int*    cand2 = (int*)(ws + 2383872);          // 256 KB
    int*    cand3 = (int*)(ws + 2646016);          // 256 KB
    int*    hist  = (int*)(ws + 2908160);          // 8 KB
    float*  xnorm = (float*)(ws + 2916352);        // 256 KB
    float*  bestd = (float*)(ws + 3178496);        // 256 KB
    double* part  = (double*)(ws + 3440640);       // 128 KB

    hipMemsetAsync(hist, 0, KCODES * sizeof(int), stream);
    k_prepw  <<<(KCODES * 64) / 256, 256, 0, stream>>>(w, wp, wnorm);
    k_gemm   <<<NROWS / 128, 1024, 0, stream>>>(x, wp, wnorm, xnorm, idxo, cand2, cand3, bestd);
    k_gather2<<<NROWS / 4, 256, 0, stream>>>(x, w, idxo, cand2, cand3, bestd, xnorm, out, hist, part);
    k_final2 <<<1, 256, 0, stream>>>(part, hist, out);
}